// Round 4
// baseline (4694.682 us; speedup 1.0000x reference)
//
#include <hip/hip_runtime.h>
#include <hip/hip_bf16.h>

// Problem constants
#define NB   256     // batch
#define NT   32      // timesteps (Tp1-1)
#define NV   10000   // vocab
#define NDF  1280    // feature channels
#define NH   512     // hidden
// 4*NH = 2048 gate width, W_DIM = 256
// ALL float inputs are fp32 (reference dtypes; values are bf16-rounded).

__device__ __forceinline__ float b2f(unsigned short u) {
    union { unsigned int i; float f; } v; v.i = ((unsigned int)u) << 16; return v.f;
}
__device__ __forceinline__ unsigned short f2b(float f) {
    union { float f; unsigned int i; } v; v.f = f;
    unsigned int r = v.i + 0x7FFF + ((v.i >> 16) & 1);   // round-to-nearest-even
    return (unsigned short)(r >> 16);
}

// Workspace layout. Float region (offsets in floats):
static const size_t OFF_A    = 0;                               // [256][16][512]
static const size_t OFF_H0   = OFF_A    + (size_t)256*16*512;   // [256][512]
static const size_t OFF_C    = OFF_H0   + (size_t)256*512;      // [256][512]
static const size_t OFF_ATTN = OFF_C    + (size_t)256*512;      // [256][512]
static const size_t OFF_HALL = OFF_ATTN + (size_t)256*512;      // [32][256][512]
static const size_t OFF_PMAX = OFF_HALL + (size_t)32*256*512;   // [8192][20]
static const size_t OFF_PSUM = OFF_PMAX + (size_t)8192*20;      // [8192][20]
static const size_t OFF_TGT  = OFF_PSUM + (size_t)8192*20;      // [8192]
static const size_t OFF_LOSS = OFF_TGT  + (size_t)8192;         // [1]
// bf16 region (internal xp activations) after float region, 16-aligned:
static const size_t XP_BYTE_OFF = ((OFF_LOSS + 1) * sizeof(float) + 15) & ~(size_t)15;
// XP: [32][256][2048] bf16 (ushort)

// ---------------------------------------------------------------------------
// K1: A[n][p][h] = sum_c feats[n,c,p]*W_proj[c,h] + b_proj[h]; h0 = mean_p A
__global__ __launch_bounds__(256) void proj_kernel(
    const float* __restrict__ feats, const float* __restrict__ Wp,
    const float* __restrict__ bp, float* __restrict__ A,
    float* __restrict__ h0, float* __restrict__ c0)
{
    const int n = blockIdx.x, tid = threadIdx.x;
    __shared__ float fl[64][16];
    float acc0[16], acc1[16];
#pragma unroll
    for (int p = 0; p < 16; p++) { acc0[p] = 0.f; acc1[p] = 0.f; }
    const float* fn = feats + (size_t)n * (NDF * 16);
    const int l = tid * 4, cc = l >> 4, ij = l & 15;
    for (int c0i = 0; c0i < NDF; c0i += 64) {
        __syncthreads();
        float4 v = *(const float4*)(fn + (c0i + cc) * 16 + ij);
        fl[cc][ij]   = v.x; fl[cc][ij+1] = v.y;
        fl[cc][ij+2] = v.z; fl[cc][ij+3] = v.w;
        __syncthreads();
        for (int c2 = 0; c2 < 64; c2++) {
            float w0 = Wp[(size_t)(c0i + c2) * NH + tid];
            float w1 = Wp[(size_t)(c0i + c2) * NH + tid + 256];
#pragma unroll
            for (int p = 0; p < 16; p++) {
                float f = fl[c2][p];
                acc0[p] += f * w0;
                acc1[p] += f * w1;
            }
        }
    }
    float bp0 = bp[tid], bp1 = bp[tid + 256];
    float s0 = 0.f, s1 = 0.f;
#pragma unroll
    for (int p = 0; p < 16; p++) {
        float a0 = acc0[p] + bp0, a1 = acc1[p] + bp1;
        A[(size_t)n * 8192 + p * 512 + tid]       = a0;
        A[(size_t)n * 8192 + p * 512 + tid + 256] = a1;
        s0 += a0; s1 += a1;
    }
    h0[n * 512 + tid]       = s0 * 0.0625f;
    h0[n * 512 + tid + 256] = s1 * 0.0625f;
    c0[n * 512 + tid]       = s0 * 0.0625f;
    c0[n * 512 + tid + 256] = s1 * 0.0625f;
}

// ---------------------------------------------------------------------------
// K2: xp[t][n][j] = W_embed[cap[n][t]] @ Wx + b, stored bf16 (internal)
__global__ __launch_bounds__(256) void xproj_kernel(
    const int* __restrict__ caps, const float* __restrict__ We,
    const float* __restrict__ Wx, const float* __restrict__ bb,
    unsigned short* __restrict__ xp)
{
    const int bt = blockIdx.x, rt = bt >> 2, ct = bt & 3;
    const int tid = threadIdx.x;
    const int r0 = rt * 16;
    const int col0 = ct * 512 + tid, col1 = col0 + 256;
    __shared__ float el[16][256];
    for (int r = 0; r < 16; r++) {
        int row = r0 + r;
        int idx = caps[(row >> 5) * 33 + (row & 31)];   // cap_in[n][t]
        el[r][tid] = We[(size_t)idx * 256 + tid];
    }
    __syncthreads();
    float acc0[16], acc1[16];
#pragma unroll
    for (int r = 0; r < 16; r++) { acc0[r] = 0.f; acc1[r] = 0.f; }
    for (int k0 = 0; k0 < 256; k0 += 4) {
        const float* w = Wx + (size_t)k0 * 2048;
        float w00 = w[col0], w01 = w[2048 + col0], w02 = w[4096 + col0], w03 = w[6144 + col0];
        float w10 = w[col1], w11 = w[2048 + col1], w12 = w[4096 + col1], w13 = w[6144 + col1];
#pragma unroll
        for (int r = 0; r < 16; r++) {
            float4 e4 = *(const float4*)&el[r][k0];
            acc0[r] += e4.x*w00 + e4.y*w01 + e4.z*w02 + e4.w*w03;
            acc1[r] += e4.x*w10 + e4.y*w11 + e4.z*w12 + e4.w*w13;
        }
    }
    float b0 = bb[col0], b1 = bb[col1];
#pragma unroll
    for (int r = 0; r < 16; r++) {
        int row = r0 + r;
        int nn = row >> 5, tt = row & 31;
        size_t base = (size_t)tt * 524288 + (size_t)nn * 2048;
        xp[base + col0] = f2b(acc0[r] + b0);
        xp[base + col1] = f2b(acc1[r] + b1);
    }
}

// ---------------------------------------------------------------------------
// K3 (per step): softmax attention. grid 256 (per n), 256 threads.
__global__ __launch_bounds__(256) void attn_kernel(
    const float* __restrict__ A, const float* __restrict__ h,
    float* __restrict__ attn)
{
    const int n = blockIdx.x, tid = threadIdx.x;
    const float* An = A + (size_t)n * 8192;
    float hv0 = h[n * 512 + tid];
    float hv1 = h[n * 512 + tid + 256];
    float av0[16], av1[16], s[16];
#pragma unroll
    for (int p = 0; p < 16; p++) {
        av0[p] = An[p * 512 + tid];
        av1[p] = An[p * 512 + tid + 256];
        s[p] = hv0 * av0[p] + hv1 * av1[p];
    }
#pragma unroll
    for (int p = 0; p < 16; p++) {
#pragma unroll
        for (int off = 32; off; off >>= 1) s[p] += __shfl_down(s[p], off, 64);
    }
    __shared__ float red[4][16];
    __shared__ float wts[16];
    const int wid = tid >> 6, lane = tid & 63;
    if (lane == 0) {
#pragma unroll
        for (int p = 0; p < 16; p++) red[wid][p] = s[p];
    }
    __syncthreads();
    if (tid == 0) {
        const float scale = 0.04419417382415922f;  // 1/sqrt(512)
        float sc[16], mx = -1e30f;
#pragma unroll
        for (int p = 0; p < 16; p++) {
            sc[p] = (red[0][p] + red[1][p] + red[2][p] + red[3][p]) * scale;
            mx = fmaxf(mx, sc[p]);
        }
        float sum = 0.f;
#pragma unroll
        for (int p = 0; p < 16; p++) { sc[p] = expf(sc[p] - mx); sum += sc[p]; }
        float inv = 1.f / sum;
#pragma unroll
        for (int p = 0; p < 16; p++) wts[p] = sc[p] * inv;
    }
    __syncthreads();
    float a0 = 0.f, a1 = 0.f;
#pragma unroll
    for (int p = 0; p < 16; p++) { a0 += av0[p] * wts[p]; a1 += av1[p] * wts[p]; }
    attn[n * 512 + tid]       = a0;
    attn[n * 512 + tid + 256] = a1;
}

// ---------------------------------------------------------------------------
// K4 (per step): a = xp_t + h@Wh + attn@Wattn; gates; c,h update.
__global__ __launch_bounds__(256) void lstm_step_kernel(
    const unsigned short* __restrict__ xp_t, const float* __restrict__ h_in,
    const float* __restrict__ attn, const float* __restrict__ Wh,
    const float* __restrict__ Wattn, float* __restrict__ c,
    float* __restrict__ h_out)
{
    const int bt = blockIdx.x, rt = bt >> 4, gt = bt & 15;
    const int tid = threadIdx.x;
    const int r0 = rt * 16;
    const int g = tid & 31, rh = tid >> 5;
    const int gcol = gt * 32 + g;
    __shared__ float hs[16][512];          // 32 KiB
    float acc[2][4] = {{0.f,0.f,0.f,0.f},{0.f,0.f,0.f,0.f}};
    const int row0 = rh, row1 = rh + 8;
    for (int phase = 0; phase < 2; phase++) {
        const float* src = phase ? attn : h_in;
        const float* W = phase ? Wattn : Wh;
        __syncthreads();
#pragma unroll
        for (int i = 0; i < 8; i++) {
            int fid = tid + i * 256;       // 2048 float4s
            int r = fid >> 7;
            int kk = (fid & 127) << 2;
            *(float4*)&hs[r][kk] = *(const float4*)(src + (size_t)(r0 + r) * 512 + kk);
        }
        __syncthreads();
        for (int k0 = 0; k0 < 512; k0 += 4) {
            const float* Wk = W + (size_t)k0 * 2048;
            float4 h40 = *(const float4*)&hs[row0][k0];
            float4 h41 = *(const float4*)&hs[row1][k0];
#pragma unroll
            for (int ty = 0; ty < 4; ty++) {
                float w0 = Wk[0*2048 + ty*512 + gcol];
                float w1 = Wk[1*2048 + ty*512 + gcol];
                float w2 = Wk[2*2048 + ty*512 + gcol];
                float w3 = Wk[3*2048 + ty*512 + gcol];
                acc[0][ty] += h40.x*w0 + h40.y*w1 + h40.z*w2 + h40.w*w3;
                acc[1][ty] += h41.x*w0 + h41.y*w1 + h41.z*w2 + h41.w*w3;
            }
        }
    }
#pragma unroll
    for (int rr = 0; rr < 2; rr++) {
        const int n = r0 + (rr ? row1 : row0);
        float ai = acc[rr][0] + b2f(xp_t[(size_t)n*2048 + gcol]);
        float af = acc[rr][1] + b2f(xp_t[(size_t)n*2048 +  512 + gcol]);
        float ao = acc[rr][2] + b2f(xp_t[(size_t)n*2048 + 1024 + gcol]);
        float ag = acc[rr][3] + b2f(xp_t[(size_t)n*2048 + 1536 + gcol]);
        float ig = 1.f / (1.f + expf(-ai));
        float fg = 1.f / (1.f + expf(-af));
        float og = 1.f / (1.f + expf(-ao));
        float gg = tanhf(ag);
        float cold = c[n * 512 + gcol];
        float cn = fg * cold + ig * gg;
        float hn = og * tanhf(cn);
        c[n * 512 + gcol]     = cn;
        h_out[n * 512 + gcol] = hn;
    }
}

// ---------------------------------------------------------------------------
// K5: fused vocab GEMM + per-(row, vtile) logsumexp partials + target extract.
__global__ __launch_bounds__(256) void vocab_partial_kernel(
    const float* __restrict__ hall, const float* __restrict__ Wv,
    const float* __restrict__ bv, const int* __restrict__ caps,
    float* __restrict__ pmax, float* __restrict__ psum, float* __restrict__ tgt)
{
    const int vt = blockIdx.x;       // 0..19
    const int rt = blockIdx.y;       // 0..255
    const int tid = threadIdx.x;
    const int r0 = rt * 32;
    const int v0 = vt * 512;
    const int col0 = v0 + tid;            // always < 10000 (max 9983)
    const int col1 = v0 + 256 + tid;
    const bool valid1 = (col1 < NV);

    __shared__ float hls[32 * 256];       // 32 KiB

    float acc0[32], acc1[32];
#pragma unroll
    for (int r = 0; r < 32; r++) { acc0[r] = 0.f; acc1[r] = 0.f; }

    for (int half = 0; half < 2; half++) {
        const int koff = half * 256;
        __syncthreads();
#pragma unroll
        for (int i = 0; i < 8; i++) {
            int fid = tid + i * 256;      // 2048 float4s
            int r = fid >> 6;
            int kk = (fid & 63) << 2;
            *(float4*)&hls[r * 256 + kk] =
                *(const float4*)(hall + (size_t)(r0 + r) * 512 + koff + kk);
        }
        __syncthreads();
        for (int k0 = 0; k0 < 256; k0 += 4) {
            const float* w = Wv + (size_t)(koff + k0) * NV;
            float w00 = w[col0];
            float w01 = w[NV + col0];
            float w02 = w[2*NV + col0];
            float w03 = w[3*NV + col0];
            float w10 = 0.f, w11 = 0.f, w12 = 0.f, w13 = 0.f;
            if (valid1) {
                w10 = w[col1];        w11 = w[NV + col1];
                w12 = w[2*NV + col1]; w13 = w[3*NV + col1];
            }
#pragma unroll
            for (int r = 0; r < 32; r++) {
                float4 h4 = *(const float4*)&hls[r * 256 + k0];
                acc0[r] += h4.x*w00 + h4.y*w01 + h4.z*w02 + h4.w*w03;
                acc1[r] += h4.x*w10 + h4.y*w11 + h4.z*w12 + h4.w*w13;
            }
        }
    }

    float bv0 = bv[col0];
    float bv1 = valid1 ? bv[col1] : 0.f;
#pragma unroll
    for (int r = 0; r < 32; r++) {
        acc0[r] += bv0;
        acc1[r] = valid1 ? (acc1[r] + bv1) : -1e30f;
    }

    // target score extraction
#pragma unroll
    for (int r = 0; r < 32; r++) {
        int row = r0 + r;
        int t = row >> 8, n = row & 255;
        int tv = caps[n * 33 + t + 1];    // cap_out[n][t]
        if (tv == col0) tgt[row] = acc0[r];
        if (valid1 && tv == col1) tgt[row] = acc1[r];
    }

    __syncthreads();                       // hls reads done; reuse as scratch
    float* red  = hls;                     // [32][4]
    float* Mrow = hls + 128;               // [32]
    float* red2 = hls + 192;               // [32][4]
    const int wid = tid >> 6, lane = tid & 63;

#pragma unroll
    for (int r = 0; r < 32; r++) {
        float m = fmaxf(acc0[r], acc1[r]);
#pragma unroll
        for (int off = 32; off; off >>= 1) m = fmaxf(m, __shfl_xor(m, off, 64));
        if (lane == 0) red[r * 4 + wid] = m;
    }
    __syncthreads();
    if (tid < 32) {
        Mrow[tid] = fmaxf(fmaxf(red[tid*4+0], red[tid*4+1]),
                          fmaxf(red[tid*4+2], red[tid*4+3]));
    }
    __syncthreads();
#pragma unroll
    for (int r = 0; r < 32; r++) {
        float M = Mrow[r];
        float e = __expf(acc0[r] - M);
        if (valid1) e += __expf(acc1[r] - M);
#pragma unroll
        for (int off = 32; off; off >>= 1) e += __shfl_xor(e, off, 64);
        if (lane == 0) red2[r * 4 + wid] = e;
    }
    __syncthreads();
    if (tid < 32) {
        int row = r0 + tid;
        pmax[row * 20 + vt] = Mrow[tid];
        psum[row * 20 + vt] = red2[tid*4+0] + red2[tid*4+1] + red2[tid*4+2] + red2[tid*4+3];
    }
}

// ---------------------------------------------------------------------------
// K6: combine partials -> nll, mask, sum/256 -> loss (float scratch)
__global__ __launch_bounds__(256) void loss_reduce_kernel(
    const float* __restrict__ pmax, const float* __restrict__ psum,
    const float* __restrict__ tgt, const int* __restrict__ caps,
    float* __restrict__ loss)
{
    const int row = blockIdx.x * 256 + threadIdx.x;   // 0..8191
    float nll = 0.f;
    const int t = row >> 8, n = row & 255;
    const int tv = caps[n * 33 + t + 1];
    if (tv != 0) {
        float M = -1e30f;
#pragma unroll
        for (int vt = 0; vt < 20; vt++) M = fmaxf(M, pmax[row * 20 + vt]);
        float S = 0.f;
#pragma unroll
        for (int vt = 0; vt < 20; vt++) S += psum[row * 20 + vt] * expf(pmax[row * 20 + vt] - M);
        nll = logf(S) + M - tgt[row];
    }
#pragma unroll
    for (int off = 32; off; off >>= 1) nll += __shfl_down(nll, off, 64);
    __shared__ float r4[4];
    if ((threadIdx.x & 63) == 0) r4[threadIdx.x >> 6] = nll;
    __syncthreads();
    if (threadIdx.x == 0)
        atomicAdd(loss, (r4[0] + r4[1] + r4[2] + r4[3]) * (1.f / 256.f));
}

// Output is the reference's fp32 scalar loss.
__global__ void finalize_kernel(const float* __restrict__ loss,
                                float* __restrict__ out)
{
    if (threadIdx.x == 0 && blockIdx.x == 0) out[0] = loss[0];
}

// ---------------------------------------------------------------------------
extern "C" void kernel_launch(void* const* d_in, const int* in_sizes, int n_in,
                              void* d_out, int out_size, void* d_ws, size_t ws_size,
                              hipStream_t stream) {
    const float* feats = (const float*)d_in[0];
    const int*   caps  = (const int*)d_in[1];
    const float* Wp    = (const float*)d_in[2];
    const float* bp    = (const float*)d_in[3];
    const float* We    = (const float*)d_in[4];
    const float* Wx    = (const float*)d_in[5];
    const float* Wh    = (const float*)d_in[6];
    const float* Wattn = (const float*)d_in[7];
    const float* bb    = (const float*)d_in[8];
    const float* Wv    = (const float*)d_in[9];
    const float* bv    = (const float*)d_in[10];
    float* ws = (float*)d_ws;
    unsigned short* xp = (unsigned short*)((char*)d_ws + XP_BYTE_OFF);

    hipMemsetAsync((char*)d_ws + OFF_LOSS * sizeof(float), 0, sizeof(float), stream);

    proj_kernel<<<256, 256, 0, stream>>>(feats, Wp, bp, ws + OFF_A, ws + OFF_H0, ws + OFF_C);
    xproj_kernel<<<2048, 256, 0, stream>>>(caps, We, Wx, bb, xp);

    for (int t = 0; t < NT; t++) {
        const float* h_in = (t == 0) ? (ws + OFF_H0)
                                     : (ws + OFF_HALL + (size_t)(t - 1) * 131072);
        attn_kernel<<<256, 256, 0, stream>>>(ws + OFF_A, h_in, ws + OFF_ATTN);
        lstm_step_kernel<<<256, 256, 0, stream>>>(
            xp + (size_t)t * 524288, h_in, ws + OFF_ATTN,
            Wh, Wattn, ws + OFF_C, ws + OFF_HALL + (size_t)t * 131072);
    }

    dim3 gv(20, 256);
    vocab_partial_kernel<<<gv, 256, 0, stream>>>(
        ws + OFF_HALL, Wv, bv, caps, ws + OFF_PMAX, ws + OFF_PSUM, ws + OFF_TGT);
    loss_reduce_kernel<<<32, 256, 0, stream>>>(
        ws + OFF_PMAX, ws + OFF_PSUM, ws + OFF_TGT, caps, ws + OFF_LOSS);
    finalize_kernel<<<1, 64, 0, stream>>>(ws + OFF_LOSS, (float*)d_out);
}

// Round 5
// 4323.883 us; speedup vs baseline: 1.0858x; 1.0858x over previous
//
#include <hip/hip_runtime.h>
#include <hip/hip_bf16.h>

// Problem constants
#define NB   256
#define NT   32
#define NV   10000
#define NVP  10240   // padded vocab for MFMA tiles
#define NDF  1280
#define NH   512

typedef short bf16x8 __attribute__((ext_vector_type(8)));   // 8 bf16 = 4 VGPRs
typedef float f32x4  __attribute__((ext_vector_type(4)));
typedef unsigned short u16;

__device__ __forceinline__ float b2f(u16 u) {
    union { unsigned i; float f; } v; v.i = ((unsigned)u) << 16; return v.f;
}
__device__ __forceinline__ u16 f2b(float f) {
    union { float f; unsigned i; } v; v.f = f;
    unsigned r = v.i + 0x7FFF + ((v.i >> 16) & 1);   // RNE
    return (u16)(r >> 16);
}

// ---------------- workspace layout (byte offsets, all 16-aligned) ----------
static const size_t B_H0    = 0;                         // [256][512] f32
static const size_t B_C     = B_H0    + 524288;          // [256][512] f32
static const size_t B_HP    = B_C     + 524288;          // h ping f32
static const size_t B_HN    = B_HP    + 524288;          // h pong f32
static const size_t B_PMAX  = B_HN    + 524288;          // [8192][20] f32
static const size_t B_PSUM  = B_PMAX  + 655360;          // [8192][20] f32
static const size_t B_TGT   = B_PSUM  + 655360;          // [8192] f32
static const size_t B_LOSS  = B_TGT   + 32768;           // [1] f32 (+pad)
static const size_t B_AB    = B_LOSS  + 16;              // [4096][512] bf16 (A)
static const size_t B_XPB   = B_AB    + 4194304;         // [32][256][2048] bf16
static const size_t B_HALLB = B_XPB   + 33554432;        // [32][256][512] bf16
static const size_t B_WVT   = B_HALLB + 8388608;         // [10240][512] bf16 (Wv^T)
static const size_t B_WXT   = B_WVT   + 10485760;        // [2048][256] bf16 (Wx^T)
// total ~61 MB

// ---------------------------------------------------------------------------
// T0: generic transpose+convert: src f32 [K][N] -> dst bf16 [Npad][K]
// grid (ceil(Npad/64), K/64), 256 thr. Zero-fills rows N..Npad.
__global__ __launch_bounds__(256) void tconv_kernel(
    const float* __restrict__ src, u16* __restrict__ dst, int K, int N, int Npad)
{
    __shared__ u16 tile[64][65];
    const int k0 = blockIdx.y * 64, n0 = blockIdx.x * 64, tid = threadIdx.x;
#pragma unroll
    for (int i = 0; i < 16; i++) {
        int idx = tid + i * 256;
        int kk = idx >> 6, nn = idx & 63;
        int n = n0 + nn;
        float v = (n < N) ? src[(size_t)(k0 + kk) * N + n] : 0.f;
        tile[kk][nn] = f2b(v);
    }
    __syncthreads();
#pragma unroll
    for (int i = 0; i < 16; i++) {
        int idx = tid + i * 256;
        int nn = idx >> 6, kk = idx & 63;
        int n = n0 + nn;
        if (n < Npad) dst[(size_t)n * K + k0 + kk] = tile[kk][nn];
    }
}

// ---------------------------------------------------------------------------
// K1: A = feats.Wp + bp (bf16 out), h0 = c0 = mean_p A (f32)
__global__ __launch_bounds__(256) void proj_kernel(
    const float* __restrict__ feats, const float* __restrict__ Wp,
    const float* __restrict__ bp, u16* __restrict__ Ab,
    float* __restrict__ h0, float* __restrict__ c0)
{
    const int n = blockIdx.x, tid = threadIdx.x;
    __shared__ float fl[64][16];
    float acc0[16], acc1[16];
#pragma unroll
    for (int p = 0; p < 16; p++) { acc0[p] = 0.f; acc1[p] = 0.f; }
    const float* fn = feats + (size_t)n * (NDF * 16);
    const int l = tid * 4, cc = l >> 4, ij = l & 15;
    for (int c0i = 0; c0i < NDF; c0i += 64) {
        __syncthreads();
        float4 v = *(const float4*)(fn + (c0i + cc) * 16 + ij);
        fl[cc][ij] = v.x; fl[cc][ij+1] = v.y; fl[cc][ij+2] = v.z; fl[cc][ij+3] = v.w;
        __syncthreads();
        for (int c2 = 0; c2 < 64; c2++) {
            float w0 = Wp[(size_t)(c0i + c2) * NH + tid];
            float w1 = Wp[(size_t)(c0i + c2) * NH + tid + 256];
#pragma unroll
            for (int p = 0; p < 16; p++) {
                float f = fl[c2][p];
                acc0[p] += f * w0;
                acc1[p] += f * w1;
            }
        }
    }
    float bp0 = bp[tid], bp1 = bp[tid + 256];
    float s0 = 0.f, s1 = 0.f;
#pragma unroll
    for (int p = 0; p < 16; p++) {
        float a0 = acc0[p] + bp0, a1 = acc1[p] + bp1;
        Ab[(size_t)n * 8192 + p * 512 + tid]       = f2b(a0);
        Ab[(size_t)n * 8192 + p * 512 + tid + 256] = f2b(a1);
        s0 += a0; s1 += a1;
    }
    h0[n * 512 + tid]       = s0 * 0.0625f;
    h0[n * 512 + tid + 256] = s1 * 0.0625f;
    c0[n * 512 + tid]       = s0 * 0.0625f;
    c0[n * 512 + tid + 256] = s1 * 0.0625f;
}

// ---------------------------------------------------------------------------
// K2 (MFMA): xpb[t][n][j] = We[cap_in[n][t]] @ Wx + b  (bf16 out)
// rows ordered row = n*32 + t. grid (4 ct, 128 rt), 256 thr = 4 waves.
// wave w: cols [ct*512 + w*128, +128), rows [rt*64, +64).
__global__ __launch_bounds__(256) void xp_mfma_kernel(
    const int* __restrict__ caps, const float* __restrict__ We,
    const u16* __restrict__ Wxt, const float* __restrict__ bb,
    u16* __restrict__ xpb)
{
    const int ct = blockIdx.x, rt = blockIdx.y;
    const int tid = threadIdx.x, w = tid >> 6, lane = tid & 63;
    const int r0 = rt * 64;
    const int lm = lane & 15, lkq = lane >> 4, lk = lkq * 8;
    const int nbase = ct * 512 + w * 128;

    int capm[4];
#pragma unroll
    for (int mt = 0; mt < 4; mt++) {
        int row = r0 + mt * 16 + lm;
        capm[mt] = caps[(row >> 5) * 33 + (row & 31)];
    }
    f32x4 acc[4][8];
#pragma unroll
    for (int mt = 0; mt < 4; mt++)
#pragma unroll
        for (int nt = 0; nt < 8; nt++) acc[mt][nt] = (f32x4){0.f, 0.f, 0.f, 0.f};

    for (int kc = 0; kc < 256; kc += 32) {
        bf16x8 af[4];
#pragma unroll
        for (int mt = 0; mt < 4; mt++) {
            const float* ap = We + (size_t)capm[mt] * 256 + kc + lk;
            float4 f0 = *(const float4*)ap;
            float4 f1 = *(const float4*)(ap + 4);
            bf16x8 t;
            t[0] = (short)f2b(f0.x); t[1] = (short)f2b(f0.y);
            t[2] = (short)f2b(f0.z); t[3] = (short)f2b(f0.w);
            t[4] = (short)f2b(f1.x); t[5] = (short)f2b(f1.y);
            t[6] = (short)f2b(f1.z); t[7] = (short)f2b(f1.w);
            af[mt] = t;
        }
#pragma unroll
        for (int nt = 0; nt < 8; nt++) {
            bf16x8 bfg = *(const bf16x8*)(Wxt + (size_t)(nbase + nt * 16 + lm) * 256 + kc + lk);
#pragma unroll
            for (int mt = 0; mt < 4; mt++)
                acc[mt][nt] = __builtin_amdgcn_mfma_f32_16x16x32_bf16(af[mt], bfg, acc[mt][nt], 0, 0, 0);
        }
    }
    float bbv[8];
#pragma unroll
    for (int nt = 0; nt < 8; nt++) bbv[nt] = bb[nbase + nt * 16 + lm];
#pragma unroll
    for (int mt = 0; mt < 4; mt++)
#pragma unroll
        for (int nt = 0; nt < 8; nt++)
#pragma unroll
            for (int r = 0; r < 4; r++) {
                int row = r0 + mt * 16 + lkq * 4 + r;   // row = n*32 + t
                int col = nbase + nt * 16 + lm;
                float v = acc[mt][nt][r] + bbv[nt];
                xpb[((size_t)(row & 31) * 256 + (row >> 5)) * 2048 + col] = f2b(v);
            }
}

// ---------------------------------------------------------------------------
// K3 (per step, fused): softmax attention + gates + c/h update.
// grid 256 = 16 rt (16 rows) x 16 gt (32 base gate cols x 4 types).
__global__ __launch_bounds__(256) void lstm_fused_kernel(
    const u16* __restrict__ xpt, const float* __restrict__ h_in,
    float* __restrict__ h_out, const u16* __restrict__ Ab,
    const float* __restrict__ Wh, const float* __restrict__ Wattn,
    float* __restrict__ c, u16* __restrict__ hallbt)
{
    const int bt = blockIdx.x, rt = bt >> 4, gt = bt & 15;
    const int tid = threadIdx.x;
    const int r0 = rt * 16;
    __shared__ float hs[16 * 516];        // padded stride 516 (conflict-free)
    __shared__ u16   at[16 * 520];        // attn vector, bf16
    __shared__ float wts[16][17];

    // stage h rows (f32)
#pragma unroll
    for (int i = 0; i < 8; i++) {
        int fid = tid + i * 256;
        int r = fid >> 7, kk = (fid & 127) << 2;
        *(float4*)&hs[r * 516 + kk] = *(const float4*)(h_in + (size_t)(r0 + r) * 512 + kk);
    }
    __syncthreads();

    // scores + softmax: thread (r = tid>>4, p = tid&15)
    {
        const int r = tid >> 4, p = tid & 15;
        const u16* ap = Ab + ((size_t)(r0 + r) * 16 + p) * 512;
        float s = 0.f;
        for (int k = 0; k < 512; k += 8) {
            ushort4 a0 = *(const ushort4*)(ap + k);
            ushort4 a1 = *(const ushort4*)(ap + k + 4);
            s += b2f(a0.x) * hs[r * 516 + k]     + b2f(a0.y) * hs[r * 516 + k + 1]
               + b2f(a0.z) * hs[r * 516 + k + 2] + b2f(a0.w) * hs[r * 516 + k + 3]
               + b2f(a1.x) * hs[r * 516 + k + 4] + b2f(a1.y) * hs[r * 516 + k + 5]
               + b2f(a1.z) * hs[r * 516 + k + 6] + b2f(a1.w) * hs[r * 516 + k + 7];
        }
        s *= 0.04419417382415922f;   // 1/sqrt(512)
        float m = s;
#pragma unroll
        for (int mask = 1; mask <= 8; mask <<= 1) m = fmaxf(m, __shfl_xor(m, mask, 64));
        float e = __expf(s - m);
        float sum = e;
#pragma unroll
        for (int mask = 1; mask <= 8; mask <<= 1) sum += __shfl_xor(sum, mask, 64);
        wts[r][p] = e / sum;
    }
    __syncthreads();

    // attn vector: thread (r = tid>>4, hc = tid&15), 32 h each -> at bf16
    {
        const int r = tid >> 4, hc = tid & 15;
        float av[32];
#pragma unroll
        for (int j = 0; j < 32; j++) av[j] = 0.f;
        const u16* abase = Ab + (size_t)(r0 + r) * 8192 + hc * 32;
        for (int p = 0; p < 16; p++) {
            float wp = wts[r][p];
            const u16* app = abase + p * 512;
#pragma unroll
            for (int j = 0; j < 32; j += 4) {
                ushort4 a4 = *(const ushort4*)(app + j);
                av[j]     += wp * b2f(a4.x);
                av[j + 1] += wp * b2f(a4.y);
                av[j + 2] += wp * b2f(a4.z);
                av[j + 3] += wp * b2f(a4.w);
            }
        }
#pragma unroll
        for (int j = 0; j < 32; j++) at[r * 520 + hc * 32 + j] = f2b(av[j]);
    }
    __syncthreads();

    // gates: thread (g = tid&31, rh = tid>>5), rows rh & rh+8, 4 types
    const int g = tid & 31, rh = tid >> 5;
    const int gcol = gt * 32 + g;
    float acc[2][4] = {{0.f,0.f,0.f,0.f},{0.f,0.f,0.f,0.f}};
    const int row0 = rh, row1 = rh + 8;
    for (int k0 = 0; k0 < 512; k0 += 4) {              // h @ Wh
        const float* Wk = Wh + (size_t)k0 * 2048;
        float4 h40 = *(const float4*)&hs[row0 * 516 + k0];
        float4 h41 = *(const float4*)&hs[row1 * 516 + k0];
#pragma unroll
        for (int ty = 0; ty < 4; ty++) {
            float w0 = Wk[0*2048 + ty*512 + gcol];
            float w1 = Wk[1*2048 + ty*512 + gcol];
            float w2 = Wk[2*2048 + ty*512 + gcol];
            float w3 = Wk[3*2048 + ty*512 + gcol];
            acc[0][ty] += h40.x*w0 + h40.y*w1 + h40.z*w2 + h40.w*w3;
            acc[1][ty] += h41.x*w0 + h41.y*w1 + h41.z*w2 + h41.w*w3;
        }
    }
    for (int k0 = 0; k0 < 512; k0 += 4) {              // attn @ Wattn
        const float* Wk = Wattn + (size_t)k0 * 2048;
        ushort4 u0 = *(const ushort4*)&at[row0 * 520 + k0];
        ushort4 u1 = *(const ushort4*)&at[row1 * 520 + k0];
        float a0x = b2f(u0.x), a0y = b2f(u0.y), a0z = b2f(u0.z), a0w = b2f(u0.w);
        float a1x = b2f(u1.x), a1y = b2f(u1.y), a1z = b2f(u1.z), a1w = b2f(u1.w);
#pragma unroll
        for (int ty = 0; ty < 4; ty++) {
            float w0 = Wk[0*2048 + ty*512 + gcol];
            float w1 = Wk[1*2048 + ty*512 + gcol];
            float w2 = Wk[2*2048 + ty*512 + gcol];
            float w3 = Wk[3*2048 + ty*512 + gcol];
            acc[0][ty] += a0x*w0 + a0y*w1 + a0z*w2 + a0w*w3;
            acc[1][ty] += a1x*w0 + a1y*w1 + a1z*w2 + a1w*w3;
        }
    }
#pragma unroll
    for (int rr = 0; rr < 2; rr++) {
        const int n = r0 + (rr ? row1 : row0);
        const u16* xq = xpt + (size_t)n * 2048;
        float ai = acc[rr][0] + b2f(xq[gcol]);
        float af = acc[rr][1] + b2f(xq[512 + gcol]);
        float ao = acc[rr][2] + b2f(xq[1024 + gcol]);
        float ag = acc[rr][3] + b2f(xq[1536 + gcol]);
        float ig = 1.f / (1.f + __expf(-ai));
        float fg = 1.f / (1.f + __expf(-af));
        float og = 1.f / (1.f + __expf(-ao));
        float gg = tanhf(ag);
        float cold = c[n * 512 + gcol];
        float cn = fg * cold + ig * gg;
        float hn = og * tanhf(cn);
        c[n * 512 + gcol]     = cn;
        h_out[n * 512 + gcol] = hn;
        hallbt[(size_t)n * 512 + gcol] = f2b(hn);
    }
}

// ---------------------------------------------------------------------------
// K4 (MFMA): vocab scores + fused per-(row,vtile) logsumexp + target extract.
// grid (20 vt, 128 rt of 64 rows), 256 thr = 4 waves (wave = 128 cols).
__global__ __launch_bounds__(256) void vocab_mfma_kernel(
    const u16* __restrict__ hallb, const u16* __restrict__ Wvt,
    const float* __restrict__ bv, const int* __restrict__ caps,
    float* __restrict__ pmax, float* __restrict__ psum, float* __restrict__ tgt)
{
    const int vt = blockIdx.x, rt = blockIdx.y;
    const int tid = threadIdx.x, w = tid >> 6, lane = tid & 63;
    const int r0 = rt * 64;
    const int lm = lane & 15, lkq = lane >> 4, lk = lkq * 8;
    const int nbase = vt * 512 + w * 128;

    __shared__ int tvs[64];
    __shared__ float cm[64][4], cs[64][4];
    if (tid < 64) {
        int row = r0 + tid;                              // row = t*256 + n
        tvs[tid] = caps[(row & 255) * 33 + (row >> 8) + 1];
    }

    f32x4 acc[4][8];
#pragma unroll
    for (int mt = 0; mt < 4; mt++)
#pragma unroll
        for (int nt = 0; nt < 8; nt++) acc[mt][nt] = (f32x4){0.f, 0.f, 0.f, 0.f};

    for (int kc = 0; kc < 512; kc += 32) {
        bf16x8 af[4];
#pragma unroll
        for (int mt = 0; mt < 4; mt++)
            af[mt] = *(const bf16x8*)(hallb + (size_t)(r0 + mt * 16 + lm) * 512 + kc + lk);
#pragma unroll
        for (int nt = 0; nt < 8; nt++) {
            bf16x8 bfg = *(const bf16x8*)(Wvt + (size_t)(nbase + nt * 16 + lm) * 512 + kc + lk);
#pragma unroll
            for (int mt = 0; mt < 4; mt++)
                acc[mt][nt] = __builtin_amdgcn_mfma_f32_16x16x32_bf16(af[mt], bfg, acc[mt][nt], 0, 0, 0);
        }
    }
    __syncthreads();   // tvs visible

    float bvv[8]; bool vld[8];
#pragma unroll
    for (int nt = 0; nt < 8; nt++) {
        int col = nbase + nt * 16 + lm;
        vld[nt] = (col < NV);
        bvv[nt] = vld[nt] ? bv[col] : 0.f;
    }
#pragma unroll
    for (int mt = 0; mt < 4; mt++)
#pragma unroll
        for (int r = 0; r < 4; r++) {
            int rloc = mt * 16 + lkq * 4 + r;
            int row = r0 + rloc;
            int tv = tvs[rloc];
            float vals[8]; float m = -1e30f;
#pragma unroll
            for (int nt = 0; nt < 8; nt++) {
                int col = nbase + nt * 16 + lm;
                float v = vld[nt] ? (acc[mt][nt][r] + bvv[nt]) : -1e30f;
                vals[nt] = v;
                m = fmaxf(m, v);
                if (col == tv) tgt[row] = v;
            }
#pragma unroll
            for (int mask = 1; mask <= 8; mask <<= 1) m = fmaxf(m, __shfl_xor(m, mask, 64));
            float s = 0.f;
#pragma unroll
            for (int nt = 0; nt < 8; nt++) s += __expf(vals[nt] - m);
#pragma unroll
            for (int mask = 1; mask <= 8; mask <<= 1) s += __shfl_xor(s, mask, 64);
            if (lm == 0) { cm[rloc][w] = m; cs[rloc][w] = s; }
        }
    __syncthreads();
    if (tid < 64) {
        int row = r0 + tid;
        float M = fmaxf(fmaxf(cm[tid][0], cm[tid][1]), fmaxf(cm[tid][2], cm[tid][3]));
        float S = cs[tid][0] * __expf(cm[tid][0] - M) + cs[tid][1] * __expf(cm[tid][1] - M)
                + cs[tid][2] * __expf(cm[tid][2] - M) + cs[tid][3] * __expf(cm[tid][3] - M);
        pmax[row * 20 + vt] = M;
        psum[row * 20 + vt] = S;
    }
}

// ---------------------------------------------------------------------------
// K5: combine partials -> masked nll -> loss
__global__ __launch_bounds__(256) void loss_reduce_kernel(
    const float* __restrict__ pmax, const float* __restrict__ psum,
    const float* __restrict__ tgt, const int* __restrict__ caps,
    float* __restrict__ loss)
{
    const int row = blockIdx.x * 256 + threadIdx.x;
    float nll = 0.f;
    const int t = row >> 8, n = row & 255;
    const int tv = caps[n * 33 + t + 1];
    if (tv != 0) {
        float M = -1e30f;
#pragma unroll
        for (int vt = 0; vt < 20; vt++) M = fmaxf(M, pmax[row * 20 + vt]);
        float S = 0.f;
#pragma unroll
        for (int vt = 0; vt < 20; vt++) S += psum[row * 20 + vt] * __expf(pmax[row * 20 + vt] - M);
        nll = logf(S) + M - tgt[row];
    }
#pragma unroll
    for (int off = 32; off; off >>= 1) nll += __shfl_down(nll, off, 64);
    __shared__ float r4[4];
    if ((threadIdx.x & 63) == 0) r4[threadIdx.x >> 6] = nll;
    __syncthreads();
    if (threadIdx.x == 0)
        atomicAdd(loss, (r4[0] + r4[1] + r4[2] + r4[3]) * (1.f / 256.f));
}

__global__ void finalize_kernel(const float* __restrict__ loss, float* __restrict__ out)
{
    if (threadIdx.x == 0 && blockIdx.x == 0) out[0] = loss[0];
}

// ---------------------------------------------------------------------------
extern "C" void kernel_launch(void* const* d_in, const int* in_sizes, int n_in,
                              void* d_out, int out_size, void* d_ws, size_t ws_size,
                              hipStream_t stream) {
    const float* feats = (const float*)d_in[0];
    const int*   caps  = (const int*)d_in[1];
    const float* Wp    = (const float*)d_in[2];
    const float* bp    = (const float*)d_in[3];
    const float* We    = (const float*)d_in[4];
    const float* Wx    = (const float*)d_in[5];
    const float* Wh    = (const float*)d_in[6];
    const float* Wattn = (const float*)d_in[7];
    const float* bb    = (const float*)d_in[8];
    const float* Wv    = (const float*)d_in[9];
    const float* bv    = (const float*)d_in[10];

    char* ws = (char*)d_ws;
    float* h0    = (float*)(ws + B_H0);
    float* c     = (float*)(ws + B_C);
    float* hP    = (float*)(ws + B_HP);
    float* hN    = (float*)(ws + B_HN);
    float* pmax  = (float*)(ws + B_PMAX);
    float* psum  = (float*)(ws + B_PSUM);
    float* tgt   = (float*)(ws + B_TGT);
    float* loss  = (float*)(ws + B_LOSS);
    u16*   Ab    = (u16*)(ws + B_AB);
    u16*   xpb   = (u16*)(ws + B_XPB);
    u16*   hallb = (u16*)(ws + B_HALLB);
    u16*   wvt   = (u16*)(ws + B_WVT);
    u16*   wxt   = (u16*)(ws + B_WXT);

    hipMemsetAsync(loss, 0, sizeof(float), stream);

    tconv_kernel<<<dim3(160, 8), 256, 0, stream>>>(Wv, wvt, 512, NV, NVP);
    tconv_kernel<<<dim3(32, 4),  256, 0, stream>>>(Wx, wxt, 256, 2048, 2048);
    proj_kernel<<<256, 256, 0, stream>>>(feats, Wp, bp, Ab, h0, c);
    xp_mfma_kernel<<<dim3(4, 128), 256, 0, stream>>>(caps, We, wxt, bb, xpb);

    for (int t = 0; t < NT; t++) {
        const float* hin = (t == 0) ? h0 : ((t & 1) ? hP : hN);
        float* hout = (t & 1) ? hN : hP;
        lstm_fused_kernel<<<256, 256, 0, stream>>>(
            xpb + (size_t)t * 524288, hin, hout, Ab, Wh, Wattn, c,
            hallb + (size_t)t * 131072);
    }

    vocab_mfma_kernel<<<dim3(20, 128), 256, 0, stream>>>(
        hallb, wvt, bv, caps, pmax, psum, tgt);
    loss_reduce_kernel<<<32, 256, 0, stream>>>(pmax, psum, tgt, caps, loss);
    finalize_kernel<<<1, 64, 0, stream>>>(loss, (float*)d_out);
}

// Round 6
// 1734.334 us; speedup vs baseline: 2.7069x; 2.4931x over previous
//
#include <hip/hip_runtime.h>
#include <hip/hip_bf16.h>

#define NB   256
#define NT   32
#define NV   10000
#define NVP  10240
#define NDF  1280
#define NH   512

typedef short bf16x8 __attribute__((ext_vector_type(8)));
typedef float f32x4  __attribute__((ext_vector_type(4)));
typedef unsigned short u16;

__device__ __forceinline__ float b2f(u16 u) {
    union { unsigned i; float f; } v; v.i = ((unsigned)u) << 16; return v.f;
}
__device__ __forceinline__ u16 f2b(float f) {
    union { float f; unsigned i; } v; v.f = f;
    unsigned r = v.i + 0x7FFF + ((v.i >> 16) & 1);   // RNE
    return (u16)(r >> 16);
}

// ---------------- workspace layout (byte offsets, all 16-aligned) ----------
static const size_t B_C     = 0;                 // [256][512] f32 cell
static const size_t B_HP    = 524288;            // h f32 ping
static const size_t B_HN    = 1048576;           // h f32 pong
static const size_t B_PMAX  = 1572864;           // [8192][20] f32
static const size_t B_PSUM  = 2228224;           // [8192][20] f32
static const size_t B_TGT   = 2883584;           // [8192] f32
static const size_t B_LOSS  = 2916352;           // [1] f32 (+pad)
static const size_t B_AB    = 2916368;           // [256][16][512] bf16 (A)
static const size_t B_XPB   = 7110672;           // [32][256][2048] bf16
static const size_t B_HALLB = 40665104;          // [32][256][512] bf16
static const size_t B_WVT   = 49053712;          // [10240][512] bf16 (Wv^T)
static const size_t B_WXT   = 59539472;          // [2048][256] bf16 (Wx^T)
static const size_t B_WHAT  = 60588048;          // [2048][1024] bf16 (Wh|Wattn ^T)
static const size_t B_HX0   = 64782352;          // [256][1024] bf16 (h|attn) ping
static const size_t B_HX1   = 65306640;          // [256][1024] bf16 pong
// total ~65.8 MB

// ---------------------------------------------------------------------------
// T0: transpose+convert: src f32 [K][N] -> dst bf16 [Npad][ldK], at koff.
__global__ __launch_bounds__(256) void tconv_kernel(
    const float* __restrict__ src, u16* __restrict__ dst,
    int K, int N, int Npad, int ldK, int koff)
{
    __shared__ u16 tile[64][65];
    const int k0 = blockIdx.y * 64, n0 = blockIdx.x * 64, tid = threadIdx.x;
#pragma unroll
    for (int i = 0; i < 16; i++) {
        int idx = tid + i * 256;
        int kk = idx >> 6, nn = idx & 63;
        int n = n0 + nn;
        float v = (n < N) ? src[(size_t)(k0 + kk) * N + n] : 0.f;
        tile[kk][nn] = f2b(v);
    }
    __syncthreads();
#pragma unroll
    for (int i = 0; i < 16; i++) {
        int idx = tid + i * 256;
        int nn = idx >> 6, kk = idx & 63;
        int n = n0 + nn;
        if (n < Npad) dst[(size_t)n * ldK + koff + k0 + kk] = tile[kk][nn];
    }
}

// ---------------------------------------------------------------------------
// K1: A = feats.Wp + bp (bf16 out), h0 = c0 = mean_p A; h0 also bf16 -> hx0
__global__ __launch_bounds__(256) void proj_kernel(
    const float* __restrict__ feats, const float* __restrict__ Wp,
    const float* __restrict__ bp, u16* __restrict__ Ab,
    float* __restrict__ h0, float* __restrict__ c0, u16* __restrict__ hx0)
{
    const int n = blockIdx.x, tid = threadIdx.x;
    __shared__ float fl[64][16];
    float acc0[16], acc1[16];
#pragma unroll
    for (int p = 0; p < 16; p++) { acc0[p] = 0.f; acc1[p] = 0.f; }
    const float* fn = feats + (size_t)n * (NDF * 16);
    const int l = tid * 4, cc = l >> 4, ij = l & 15;
    for (int c0i = 0; c0i < NDF; c0i += 64) {
        __syncthreads();
        float4 v = *(const float4*)(fn + (c0i + cc) * 16 + ij);
        fl[cc][ij] = v.x; fl[cc][ij+1] = v.y; fl[cc][ij+2] = v.z; fl[cc][ij+3] = v.w;
        __syncthreads();
        for (int c2 = 0; c2 < 64; c2++) {
            float w0 = Wp[(size_t)(c0i + c2) * NH + tid];
            float w1 = Wp[(size_t)(c0i + c2) * NH + tid + 256];
#pragma unroll
            for (int p = 0; p < 16; p++) {
                float f = fl[c2][p];
                acc0[p] += f * w0;
                acc1[p] += f * w1;
            }
        }
    }
    float bp0 = bp[tid], bp1 = bp[tid + 256];
    float s0 = 0.f, s1 = 0.f;
#pragma unroll
    for (int p = 0; p < 16; p++) {
        float a0 = acc0[p] + bp0, a1 = acc1[p] + bp1;
        Ab[(size_t)n * 8192 + p * 512 + tid]       = f2b(a0);
        Ab[(size_t)n * 8192 + p * 512 + tid + 256] = f2b(a1);
        s0 += a0; s1 += a1;
    }
    s0 *= 0.0625f; s1 *= 0.0625f;
    h0[n * 512 + tid]       = s0;
    h0[n * 512 + tid + 256] = s1;
    c0[n * 512 + tid]       = s0;
    c0[n * 512 + tid + 256] = s1;
    hx0[(size_t)n * 1024 + tid]       = f2b(s0);
    hx0[(size_t)n * 1024 + tid + 256] = f2b(s1);
}

// ---------------------------------------------------------------------------
// K2 (MFMA): xpb[t][n][j] = We[cap_in[n][t]] @ Wx + b  (bf16 out)
__global__ __launch_bounds__(256) void xp_mfma_kernel(
    const int* __restrict__ caps, const float* __restrict__ We,
    const u16* __restrict__ Wxt, const float* __restrict__ bb,
    u16* __restrict__ xpb)
{
    const int ct = blockIdx.x, rt = blockIdx.y;
    const int tid = threadIdx.x, w = tid >> 6, lane = tid & 63;
    const int r0 = rt * 64;
    const int lm = lane & 15, lkq = lane >> 4, lk = lkq * 8;
    const int nbase = ct * 512 + w * 128;

    int capm[4];
#pragma unroll
    for (int mt = 0; mt < 4; mt++) {
        int row = r0 + mt * 16 + lm;
        capm[mt] = caps[(row >> 5) * 33 + (row & 31)];
    }
    f32x4 acc[4][8];
#pragma unroll
    for (int mt = 0; mt < 4; mt++)
#pragma unroll
        for (int nt = 0; nt < 8; nt++) acc[mt][nt] = (f32x4){0.f, 0.f, 0.f, 0.f};

    for (int kc = 0; kc < 256; kc += 32) {
        bf16x8 af[4];
#pragma unroll
        for (int mt = 0; mt < 4; mt++) {
            const float* ap = We + (size_t)capm[mt] * 256 + kc + lk;
            float4 f0 = *(const float4*)ap;
            float4 f1 = *(const float4*)(ap + 4);
            bf16x8 t;
            t[0] = (short)f2b(f0.x); t[1] = (short)f2b(f0.y);
            t[2] = (short)f2b(f0.z); t[3] = (short)f2b(f0.w);
            t[4] = (short)f2b(f1.x); t[5] = (short)f2b(f1.y);
            t[6] = (short)f2b(f1.z); t[7] = (short)f2b(f1.w);
            af[mt] = t;
        }
#pragma unroll
        for (int nt = 0; nt < 8; nt++) {
            bf16x8 bfg = *(const bf16x8*)(Wxt + (size_t)(nbase + nt * 16 + lm) * 256 + kc + lk);
#pragma unroll
            for (int mt = 0; mt < 4; mt++)
                acc[mt][nt] = __builtin_amdgcn_mfma_f32_16x16x32_bf16(af[mt], bfg, acc[mt][nt], 0, 0, 0);
        }
    }
    float bbv[8];
#pragma unroll
    for (int nt = 0; nt < 8; nt++) bbv[nt] = bb[nbase + nt * 16 + lm];
#pragma unroll
    for (int mt = 0; mt < 4; mt++)
#pragma unroll
        for (int nt = 0; nt < 8; nt++)
#pragma unroll
            for (int r = 0; r < 4; r++) {
                int row = r0 + mt * 16 + lkq * 4 + r;   // row = n*32 + t
                int col = nbase + nt * 16 + lm;
                float v = acc[mt][nt][r] + bbv[nt];
                xpb[((size_t)(row & 31) * 256 + (row >> 5)) * 2048 + col] = f2b(v);
            }
}

// ---------------------------------------------------------------------------
// K3 (per step): attention. 1 wave per n. Writes attn bf16 -> hx[n][512:1024].
__global__ __launch_bounds__(64) void attn_step_kernel(
    const float* __restrict__ hf, const u16* __restrict__ Ab,
    u16* __restrict__ hx)
{
    const int n = blockIdx.x, lane = threadIdx.x;
    const float* hp = hf + (size_t)n * 512 + lane * 8;
    float4 h0 = *(const float4*)hp;
    float4 h1 = *(const float4*)(hp + 4);
    const u16* abase = Ab + (size_t)n * 8192 + lane * 8;

    float sc[16];
#pragma unroll
    for (int p = 0; p < 16; p++) {
        const u16* ap = abase + p * 512;
        ushort4 a0 = *(const ushort4*)ap;
        ushort4 a1 = *(const ushort4*)(ap + 4);
        float d = h0.x*b2f(a0.x) + h0.y*b2f(a0.y) + h0.z*b2f(a0.z) + h0.w*b2f(a0.w)
                + h1.x*b2f(a1.x) + h1.y*b2f(a1.y) + h1.z*b2f(a1.z) + h1.w*b2f(a1.w);
#pragma unroll
        for (int mask = 1; mask <= 32; mask <<= 1) d += __shfl_xor(d, mask, 64);
        sc[p] = d * 0.04419417382415922f;   // 1/sqrt(512)
    }
    float mx = sc[0];
#pragma unroll
    for (int p = 1; p < 16; p++) mx = fmaxf(mx, sc[p]);
    float sum = 0.f;
#pragma unroll
    for (int p = 0; p < 16; p++) { sc[p] = __expf(sc[p] - mx); sum += sc[p]; }
    float inv = 1.f / sum;
    float av[8];
#pragma unroll
    for (int j = 0; j < 8; j++) av[j] = 0.f;
#pragma unroll
    for (int p = 0; p < 16; p++) {
        float wp = sc[p] * inv;
        const u16* ap = abase + p * 512;
        ushort4 a0 = *(const ushort4*)ap;
        ushort4 a1 = *(const ushort4*)(ap + 4);
        av[0] += wp*b2f(a0.x); av[1] += wp*b2f(a0.y); av[2] += wp*b2f(a0.z); av[3] += wp*b2f(a0.w);
        av[4] += wp*b2f(a1.x); av[5] += wp*b2f(a1.y); av[6] += wp*b2f(a1.z); av[7] += wp*b2f(a1.w);
    }
    ushort4 o0, o1;
    o0.x = f2b(av[0]); o0.y = f2b(av[1]); o0.z = f2b(av[2]); o0.w = f2b(av[3]);
    o1.x = f2b(av[4]); o1.y = f2b(av[5]); o1.z = f2b(av[6]); o1.w = f2b(av[7]);
    u16* op = hx + (size_t)n * 1024 + 512 + lane * 8;
    *(ushort4*)op = o0;
    *(ushort4*)(op + 4) = o1;
}

// ---------------------------------------------------------------------------
// K4 (per step, MFMA): gates = hx(256x1024) @ WhaT^T + xp; nonlin; c,h update.
// grid (32 hct, 4 mt), 256 thr = 4 waves; wave: 16 rows x 16 h-cols x 4 types.
__global__ __launch_bounds__(256) void gates_step_kernel(
    const u16* __restrict__ hx_in, const u16* __restrict__ what,
    const u16* __restrict__ xpt, float* __restrict__ c,
    float* __restrict__ hf_out, u16* __restrict__ hx_out,
    u16* __restrict__ hallbt)
{
    const int hct = blockIdx.x, mt = blockIdx.y;
    const int tid = threadIdx.x, w = tid >> 6, lane = tid & 63;
    const int lm = lane & 15, lkq = lane >> 4, lk = lkq * 8;
    const int mrow0 = mt * 64 + w * 16;
    const int hcol = hct * 16 + lm;

    f32x4 acc[4];
#pragma unroll
    for (int ty = 0; ty < 4; ty++) acc[ty] = (f32x4){0.f, 0.f, 0.f, 0.f};

    for (int kc = 0; kc < 1024; kc += 32) {
        bf16x8 af = *(const bf16x8*)(hx_in + (size_t)(mrow0 + lm) * 1024 + kc + lk);
#pragma unroll
        for (int ty = 0; ty < 4; ty++) {
            bf16x8 bfg = *(const bf16x8*)(what + (size_t)(ty * 512 + hcol) * 1024 + kc + lk);
            acc[ty] = __builtin_amdgcn_mfma_f32_16x16x32_bf16(af, bfg, acc[ty], 0, 0, 0);
        }
    }
#pragma unroll
    for (int r = 0; r < 4; r++) {
        const int n = mrow0 + lkq * 4 + r;
        const u16* xq = xpt + (size_t)n * 2048;
        float ai = acc[0][r] + b2f(xq[hcol]);
        float af_ = acc[1][r] + b2f(xq[512 + hcol]);
        float ao = acc[2][r] + b2f(xq[1024 + hcol]);
        float ag = acc[3][r] + b2f(xq[1536 + hcol]);
        float ig = 1.f / (1.f + __expf(-ai));
        float fg = 1.f / (1.f + __expf(-af_));
        float og = 1.f / (1.f + __expf(-ao));
        float gg = tanhf(ag);
        const int idx = n * 512 + hcol;
        float cn = fg * c[idx] + ig * gg;
        float hn = og * tanhf(cn);
        c[idx] = cn;
        hf_out[idx] = hn;
        u16 hb = f2b(hn);
        hx_out[(size_t)n * 1024 + hcol] = hb;
        hallbt[idx] = hb;
    }
}

// ---------------------------------------------------------------------------
// K5 (MFMA): vocab scores + fused per-(row,vtile) logsumexp + target extract.
__global__ __launch_bounds__(256) void vocab_mfma_kernel(
    const u16* __restrict__ hallb, const u16* __restrict__ Wvt,
    const float* __restrict__ bv, const int* __restrict__ caps,
    float* __restrict__ pmax, float* __restrict__ psum, float* __restrict__ tgt)
{
    const int vt = blockIdx.x, rt = blockIdx.y;
    const int tid = threadIdx.x, w = tid >> 6, lane = tid & 63;
    const int r0 = rt * 64;
    const int lm = lane & 15, lkq = lane >> 4, lk = lkq * 8;
    const int nbase = vt * 512 + w * 128;

    __shared__ int tvs[64];
    __shared__ float cm[64][4], cs[64][4];
    if (tid < 64) {
        int row = r0 + tid;                              // row = t*256 + n
        tvs[tid] = caps[(row & 255) * 33 + (row >> 8) + 1];
    }

    f32x4 acc[4][8];
#pragma unroll
    for (int mt = 0; mt < 4; mt++)
#pragma unroll
        for (int nt = 0; nt < 8; nt++) acc[mt][nt] = (f32x4){0.f, 0.f, 0.f, 0.f};

    for (int kc = 0; kc < 512; kc += 32) {
        bf16x8 af[4];
#pragma unroll
        for (int mt = 0; mt < 4; mt++)
            af[mt] = *(const bf16x8*)(hallb + (size_t)(r0 + mt * 16 + lm) * 512 + kc + lk);
#pragma unroll
        for (int nt = 0; nt < 8; nt++) {
            bf16x8 bfg = *(const bf16x8*)(Wvt + (size_t)(nbase + nt * 16 + lm) * 512 + kc + lk);
#pragma unroll
            for (int mt = 0; mt < 4; mt++)
                acc[mt][nt] = __builtin_amdgcn_mfma_f32_16x16x32_bf16(af[mt], bfg, acc[mt][nt], 0, 0, 0);
        }
    }
    __syncthreads();

    float bvv[8]; bool vld[8];
#pragma unroll
    for (int nt = 0; nt < 8; nt++) {
        int col = nbase + nt * 16 + lm;
        vld[nt] = (col < NV);
        bvv[nt] = vld[nt] ? bv[col] : 0.f;
    }
#pragma unroll
    for (int mt = 0; mt < 4; mt++)
#pragma unroll
        for (int r = 0; r < 4; r++) {
            int rloc = mt * 16 + lkq * 4 + r;
            int row = r0 + rloc;
            int tv = tvs[rloc];
            float vals[8]; float m = -1e30f;
#pragma unroll
            for (int nt = 0; nt < 8; nt++) {
                int col = nbase + nt * 16 + lm;
                float v = vld[nt] ? (acc[mt][nt][r] + bvv[nt]) : -1e30f;
                vals[nt] = v;
                m = fmaxf(m, v);
                if (col == tv) tgt[row] = v;
            }
#pragma unroll
            for (int mask = 1; mask <= 8; mask <<= 1) m = fmaxf(m, __shfl_xor(m, mask, 64));
            float s = 0.f;
#pragma unroll
            for (int nt = 0; nt < 8; nt++) s += __expf(vals[nt] - m);
#pragma unroll
            for (int mask = 1; mask <= 8; mask <<= 1) s += __shfl_xor(s, mask, 64);
            if (lm == 0) { cm[rloc][w] = m; cs[rloc][w] = s; }
        }
    __syncthreads();
    if (tid < 64) {
        int row = r0 + tid;
        float M = fmaxf(fmaxf(cm[tid][0], cm[tid][1]), fmaxf(cm[tid][2], cm[tid][3]));
        float S = cs[tid][0] * __expf(cm[tid][0] - M) + cs[tid][1] * __expf(cm[tid][1] - M)
                + cs[tid][2] * __expf(cm[tid][2] - M) + cs[tid][3] * __expf(cm[tid][3] - M);
        pmax[row * 20 + vt] = M;
        psum[row * 20 + vt] = S;
    }
}

// ---------------------------------------------------------------------------
__global__ __launch_bounds__(256) void loss_reduce_kernel(
    const float* __restrict__ pmax, const float* __restrict__ psum,
    const float* __restrict__ tgt, const int* __restrict__ caps,
    float* __restrict__ loss)
{
    const int row = blockIdx.x * 256 + threadIdx.x;
    float nll = 0.f;
    const int t = row >> 8, n = row & 255;
    const int tv = caps[n * 33 + t + 1];
    if (tv != 0) {
        float M = -1e30f;
#pragma unroll
        for (int vt = 0; vt < 20; vt++) M = fmaxf(M, pmax[row * 20 + vt]);
        float S = 0.f;
#pragma unroll
        for (int vt = 0; vt < 20; vt++) S += psum[row * 20 + vt] * __expf(pmax[row * 20 + vt] - M);
        nll = logf(S) + M - tgt[row];
    }
#pragma unroll
    for (int off = 32; off; off >>= 1) nll += __shfl_down(nll, off, 64);
    __shared__ float r4[4];
    if ((threadIdx.x & 63) == 0) r4[threadIdx.x >> 6] = nll;
    __syncthreads();
    if (threadIdx.x == 0)
        atomicAdd(loss, (r4[0] + r4[1] + r4[2] + r4[3]) * (1.f / 256.f));
}

__global__ void finalize_kernel(const float* __restrict__ loss, float* __restrict__ out)
{
    if (threadIdx.x == 0 && blockIdx.x == 0) out[0] = loss[0];
}

// ---------------------------------------------------------------------------
extern "C" void kernel_launch(void* const* d_in, const int* in_sizes, int n_in,
                              void* d_out, int out_size, void* d_ws, size_t ws_size,
                              hipStream_t stream) {
    const float* feats = (const float*)d_in[0];
    const int*   caps  = (const int*)d_in[1];
    const float* Wp    = (const float*)d_in[2];
    const float* bp    = (const float*)d_in[3];
    const float* We    = (const float*)d_in[4];
    const float* Wx    = (const float*)d_in[5];
    const float* Wh    = (const float*)d_in[6];
    const float* Wattn = (const float*)d_in[7];
    const float* bb    = (const float*)d_in[8];
    const float* Wv    = (const float*)d_in[9];
    const float* bv    = (const float*)d_in[10];

    char* ws = (char*)d_ws;
    float* c     = (float*)(ws + B_C);
    float* hf[2] = { (float*)(ws + B_HP), (float*)(ws + B_HN) };
    float* pmax  = (float*)(ws + B_PMAX);
    float* psum  = (float*)(ws + B_PSUM);
    float* tgt   = (float*)(ws + B_TGT);
    float* loss  = (float*)(ws + B_LOSS);
    u16*   Ab    = (u16*)(ws + B_AB);
    u16*   xpb   = (u16*)(ws + B_XPB);
    u16*   hallb = (u16*)(ws + B_HALLB);
    u16*   wvt   = (u16*)(ws + B_WVT);
    u16*   wxt   = (u16*)(ws + B_WXT);
    u16*   what  = (u16*)(ws + B_WHAT);
    u16*   hx[2] = { (u16*)(ws + B_HX0), (u16*)(ws + B_HX1) };

    hipMemsetAsync(loss, 0, sizeof(float), stream);

    tconv_kernel<<<dim3(160, 8), 256, 0, stream>>>(Wv, wvt, 512, NV, NVP, 512, 0);
    tconv_kernel<<<dim3(32, 4),  256, 0, stream>>>(Wx, wxt, 256, 2048, 2048, 256, 0);
    tconv_kernel<<<dim3(32, 8),  256, 0, stream>>>(Wh, what, 512, 2048, 2048, 1024, 0);
    tconv_kernel<<<dim3(32, 8),  256, 0, stream>>>(Wattn, what, 512, 2048, 2048, 1024, 512);
    proj_kernel<<<256, 256, 0, stream>>>(feats, Wp, bp, Ab, hf[0], c, hx[0]);
    xp_mfma_kernel<<<dim3(4, 128), 256, 0, stream>>>(caps, We, wxt, bb, xpb);

    for (int t = 0; t < NT; t++) {
        const int in = t & 1, out = 1 - in;
        attn_step_kernel<<<256, 64, 0, stream>>>(hf[in], Ab, hx[in]);
        gates_step_kernel<<<dim3(32, 4), 256, 0, stream>>>(
            hx[in], what, xpb + (size_t)t * 524288, c,
            hf[out], hx[out], hallb + (size_t)t * 131072);
    }

    vocab_mfma_kernel<<<dim3(20, 128), 256, 0, stream>>>(
        hallb, wvt, bv, caps, pmax, psum, tgt);
    loss_reduce_kernel<<<32, 256, 0, stream>>>(pmax, psum, tgt, caps, loss);
    finalize_kernel<<<1, 64, 0, stream>>>(loss, (float*)d_out);
}